// Round 3
// baseline (338.673 us; speedup 1.0000x reference)
//
#include <hip/hip_runtime.h>
#include <stdint.h>

#define DD 512
#define MTOT 32768                    // B*N = 8*4096
#define MD ((size_t)MTOT * DD)        // 16,777,216
#define WELEM 262144                  // 512*512

typedef float f32x4 __attribute__((ext_vector_type(4)));
typedef __bf16 bf16x8 __attribute__((ext_vector_type(8)));

static __device__ __forceinline__ unsigned short f2bf(float f) {
  union { float f; unsigned int u; } c; c.f = f;
  unsigned int r = c.u + 0x7fffu + ((c.u >> 16) & 1u);
  return (unsigned short)(r >> 16);
}
static __device__ __forceinline__ float bf2f(unsigned short h) {
  union { unsigned int u; float f; } c; c.u = ((unsigned int)h) << 16;
  return c.f;
}

union FragU { uint4 u; bf16x8 b; };

static __device__ __forceinline__ void load_lds16(const void* g, void* l) {
  __builtin_amdgcn_global_load_lds(
      (const __attribute__((address_space(1))) void*)g,
      (__attribute__((address_space(3))) void*)l, 16, 0, 0);
}

// ---------------- a,b fp32 -> bf16 (one launch) ---------------------------
__global__ __launch_bounds__(256) void cvt2_k(const float* __restrict__ a,
    const float* __restrict__ b, unsigned short* __restrict__ dst) {
  int i = blockIdx.x * 1024 + threadIdx.x * 4;
  const float* src = (i < (int)MD) ? (a + i) : (b + (i - (int)MD));
  float4 f = *(const float4*)src;
  ushort4 h;
  h.x = f2bf(f.x); h.y = f2bf(f.y); h.z = f2bf(f.z); h.w = f2bf(f.w);
  *(ushort4*)(dst + i) = h;
}

// ---------------- weights->bf16 (Wq,Wk,Wf) + zero stats -------------------
// blocks 0..767: weight convert; blocks 768..863: zero SSQK+Adot (3*MTOT f32)
__global__ __launch_bounds__(256) void prep_k(const float* __restrict__ Wq,
    const float* __restrict__ Wk, const float* __restrict__ Wf,
    unsigned short* __restrict__ Wqkb, unsigned short* __restrict__ Wfb,
    float* __restrict__ stats) {
  if (blockIdx.x < 768) {
    int slab = blockIdx.x >> 8;
    int off = (blockIdx.x & 255) * 1024 + threadIdx.x * 4;
    const float* s = slab == 0 ? Wq : slab == 1 ? Wk : Wf;
    unsigned short* d = slab == 0 ? Wqkb : slab == 1 ? (Wqkb + WELEM) : Wfb;
    float4 f = *(const float4*)(s + off);
    ushort4 h;
    h.x = f2bf(f.x); h.y = f2bf(f.y); h.z = f2bf(f.z); h.w = f2bf(f.w);
    *(ushort4*)(d + off) = h;
  } else {
    int off = (blockIdx.x - 768) * 1024 + threadIdx.x * 4;
    float4 z = {0.f, 0.f, 0.f, 0.f};
    *(float4*)(stats + off) = z;
  }
}

// ---------------- W'p[b] = Wp * G[b,:] ------------------------------------
__global__ __launch_bounds__(256) void scalew_k(const float* __restrict__ Wp,
    const float* __restrict__ G, unsigned short* __restrict__ out) {
  int i = blockIdx.x * 1024 + threadIdx.x * 4;  // [0, 8*262144)
  int b = i >> 18;
  int rem = i & (WELEM - 1);
  int d = rem & 511;
  float4 w = *(const float4*)(Wp + rem);
  float4 g = *(const float4*)(G + b * DD + d);
  ushort4 h;
  h.x = f2bf(w.x * g.x); h.y = f2bf(w.y * g.y);
  h.z = f2bf(w.z * g.z); h.w = f2bf(w.w * g.w);
  *(ushort4*)(out + i) = h;
}

// ---------------- shared GEMM main loop (m97: 128x128xBK64, lds-direct) ---
static __device__ __forceinline__ void gemm_main(
    const unsigned short* __restrict__ X, const unsigned short* __restrict__ W,
    unsigned short* As, unsigned short* Bs, int row0, int col0,
    f32x4 acc[4][4]) {
  const int tid = threadIdx.x;
  const int lane = tid & 63, wave = tid >> 6;
  // staging: lane L -> row L>>3, stored kseg L&7, source kseg (L&7)^(L>>3)
  const int sr = lane >> 3;
  const int scol = ((lane & 7) ^ sr) * 8;
  const unsigned short* Ag = X + (size_t)(row0 + wave * 32 + sr) * DD + scol;
  const unsigned short* Bg = W + (size_t)(col0 + wave * 32 + sr) * DD + scol;
  const int ldsb = wave * 32 * 64;
  const int fr = lane & 15, quad = lane >> 4;
  const int wr = (wave >> 1) * 64, wc = (wave & 1) * 64;
  const int sw0 = ((quad ^ (fr & 7)) * 8);
  const int sw1 = (((quad + 4) ^ (fr & 7)) * 8);

  for (int k0 = 0; k0 < DD; k0 += 64) {
#pragma unroll
    for (int q = 0; q < 4; q++) {
      load_lds16(Ag + (size_t)q * 8 * DD + k0, As + ldsb + q * 8 * 64);
      load_lds16(Bg + (size_t)q * 8 * DD + k0, Bs + ldsb + q * 8 * 64);
    }
    __syncthreads();
#pragma unroll
    for (int kk = 0; kk < 2; kk++) {
      const int sw = kk ? sw1 : sw0;
      bf16x8 af[4], bfr[4];
#pragma unroll
      for (int i = 0; i < 4; i++) {
        FragU u; u.u = *(const uint4*)&As[(wr + i * 16 + fr) * 64 + sw];
        af[i] = u.b;
      }
#pragma unroll
      for (int j = 0; j < 4; j++) {
        FragU u; u.u = *(const uint4*)&Bs[(wc + j * 16 + fr) * 64 + sw];
        bfr[j] = u.b;
      }
#pragma unroll
      for (int i = 0; i < 4; i++)
#pragma unroll
        for (int j = 0; j < 4; j++)
          acc[i][j] = __builtin_amdgcn_mfma_f32_16x16x32_bf16(af[i], bfr[j], acc[i][j], 0, 0, 0);
    }
    __syncthreads();
  }
}

// ---------------- fused Q/K GEMM + raw store + row-stats ------------------
// z=0: Q=a*Wq^T+bq, stats SSQ + Adot(=dot(.,wg)); z=1: K=b*Wk^T+bk, SSK.
__global__ __launch_bounds__(256) void gemm_qk_k(
    const unsigned short* __restrict__ Xab,
    const unsigned short* __restrict__ Wqk,
    const float* __restrict__ bq, const float* __restrict__ bk,
    const float* __restrict__ wg,
    unsigned short* __restrict__ QK,
    float* __restrict__ SS, float* __restrict__ Adot) {
  __shared__ unsigned short As[128 * 64];
  __shared__ unsigned short Bs[128 * 64];
  const int z = blockIdx.z;
  const unsigned short* X = Xab + (size_t)z * MD;
  const unsigned short* W = Wqk + (size_t)z * WELEM;
  const float* bias = z ? bk : bq;
  unsigned short* out = QK + (size_t)z * MD;
  float* SSp = SS + (size_t)z * MTOT;
  const int row0 = blockIdx.x * 128, col0 = blockIdx.y * 128;

  f32x4 acc[4][4] = {};
  gemm_main(X, W, As, Bs, row0, col0, acc);

  const int lane = threadIdx.x & 63, wave = threadIdx.x >> 6;
  const int fr = lane & 15, quad = lane >> 4;
  const int wr = (wave >> 1) * 64, wc = (wave & 1) * 64;
  float ssv[4][4] = {};
  float dtv[4][4] = {};
#pragma unroll
  for (int j = 0; j < 4; j++) {
    int gc = col0 + wc + j * 16 + fr;
    float bv = bias[gc];
    float wgv = (z == 0) ? wg[gc] : 0.f;
#pragma unroll
    for (int i = 0; i < 4; i++) {
      int gr0 = row0 + wr + i * 16 + quad * 4;
#pragma unroll
      for (int r = 0; r < 4; r++) {
        float v = acc[i][j][r] + bv;
        out[(size_t)(gr0 + r) * DD + gc] = f2bf(v);
        ssv[i][r] += v * v;
        dtv[i][r] += v * wgv;
      }
    }
  }
#pragma unroll
  for (int i = 0; i < 4; i++)
#pragma unroll
    for (int r = 0; r < 4; r++) {
      float s = ssv[i][r];
#pragma unroll
      for (int m = 1; m < 16; m <<= 1) s += __shfl_xor(s, m, 64);
      if (z == 0) {
        float d = dtv[i][r];
#pragma unroll
        for (int m = 1; m < 16; m <<= 1) d += __shfl_xor(d, m, 64);
        if (fr == 0) atomicAdd(&Adot[row0 + wr + i * 16 + quad * 4 + r], d);
      }
      if (fr == 0) atomicAdd(&SSp[row0 + wr + i * 16 + quad * 4 + r], s);
    }
}

// ---------------- per-row norms + per-batch sinv + zero G -----------------
__global__ __launch_bounds__(1024) void reduce2_k(const float* __restrict__ SSQK,
    const float* __restrict__ Adot, float* __restrict__ rnQ,
    float* __restrict__ rnK, float* __restrict__ wrow,
    float* __restrict__ sinv, float* __restrict__ G) {
  const int b = blockIdx.x, t = threadIdx.x;
  if (t < DD) G[b * DD + t] = 0.f;
  float ss = 0.f;
  for (int i = t; i < 4096; i += 1024) {
    int n = b * 4096 + i;
    float sq = SSQK[n], sk = SSQK[MTOT + n], ad = Adot[n];
    float rq = 1.0f / fmaxf(sqrtf(sq), 1e-12f);
    rnQ[n] = rq;
    rnK[n] = 1.0f / fmaxf(sqrtf(sk), 1e-12f);
    wrow[n] = ad / fmaxf(sq, 1e-24f);   // = Adot * rnQ^2
    float araw = ad * rq;
    ss += araw * araw;
  }
#pragma unroll
  for (int m = 1; m < 64; m <<= 1) ss += __shfl_xor(ss, m, 64);
  __shared__ float sred[16];
  if ((t & 63) == 0) sred[t >> 6] = ss;
  __syncthreads();
  if (t == 0) {
    float tot = 0.f;
    for (int i = 0; i < 16; i++) tot += sred[i];
    sinv[b] = 1.0f / fmaxf(sqrtf(tot), 1e-12f);
  }
}

// ---------------- G[b,d] = sum_n (wrow[n]*sinv[b]) * Qraw[b,n,d] ----------
__global__ __launch_bounds__(256) void pool_k(const float* __restrict__ wrow,
    const float* __restrict__ sinv, const unsigned short* __restrict__ Q,
    float* __restrict__ G) {
  const int b = blockIdx.x >> 5;
  const int chunk = blockIdx.x & 31;
  const int rbase = b * 4096 + chunk * 128;
  const float si = sinv[b];
  const int t = threadIdx.x;
  float a0 = 0.f, a1 = 0.f;
#pragma unroll 4
  for (int r = 0; r < 128; r++) {
    float w = wrow[rbase + r] * si;
    unsigned int q = *(const unsigned int*)(Q + (size_t)(rbase + r) * DD + 2 * t);
    a0 += w * bf2f((unsigned short)(q & 0xffff));
    a1 += w * bf2f((unsigned short)(q >> 16));
  }
  atomicAdd(&G[b * DD + 2 * t], a0);
  atomicAdd(&G[b * DD + 2 * t + 1], a1);
}

// ---------------- O1 = rnK*(K*Wps^T) + bp + rnQ*Qraw -> bf16 --------------
__global__ __launch_bounds__(256) void gemm3_k(
    const unsigned short* __restrict__ K,
    const unsigned short* __restrict__ Wps,
    const float* __restrict__ bp,
    const unsigned short* __restrict__ Qraw,
    const float* __restrict__ rnK, const float* __restrict__ rnQ,
    unsigned short* __restrict__ O1) {
  __shared__ unsigned short As[128 * 64];
  __shared__ unsigned short Bs[128 * 64];
  const int row0 = blockIdx.x * 128, col0 = blockIdx.y * 128;
  const unsigned short* W = Wps + (size_t)(row0 >> 12) * WELEM;
  f32x4 acc[4][4] = {};
  gemm_main(K, W, As, Bs, row0, col0, acc);
  const int lane = threadIdx.x & 63, wave = threadIdx.x >> 6;
  const int fr = lane & 15, quad = lane >> 4;
  const int wr = (wave >> 1) * 64, wc = (wave & 1) * 64;
  float rk[4][4], rq[4][4];
#pragma unroll
  for (int i = 0; i < 4; i++)
#pragma unroll
    for (int r = 0; r < 4; r++) {
      int row = row0 + wr + i * 16 + quad * 4 + r;
      rk[i][r] = rnK[row];
      rq[i][r] = rnQ[row];
    }
#pragma unroll
  for (int j = 0; j < 4; j++) {
    int gc = col0 + wc + j * 16 + fr;
    float bv = bp[gc];
#pragma unroll
    for (int i = 0; i < 4; i++) {
      int gr0 = row0 + wr + i * 16 + quad * 4;
#pragma unroll
      for (int r = 0; r < 4; r++) {
        size_t idx = (size_t)(gr0 + r) * DD + gc;
        float v = rk[i][r] * acc[i][j][r] + bv + rq[i][r] * bf2f(Qraw[idx]);
        O1[idx] = f2bf(v);
      }
    }
  }
}

// ---------------- out = O1*Wf^T + bf -> fp32 ------------------------------
__global__ __launch_bounds__(256) void gemm4_k(
    const unsigned short* __restrict__ X,
    const unsigned short* __restrict__ Wf,
    const float* __restrict__ bfb, float* __restrict__ out) {
  __shared__ unsigned short As[128 * 64];
  __shared__ unsigned short Bs[128 * 64];
  const int row0 = blockIdx.x * 128, col0 = blockIdx.y * 128;
  f32x4 acc[4][4] = {};
  gemm_main(X, Wf, As, Bs, row0, col0, acc);
  const int lane = threadIdx.x & 63, wave = threadIdx.x >> 6;
  const int fr = lane & 15, quad = lane >> 4;
  const int wr = (wave >> 1) * 64, wc = (wave & 1) * 64;
#pragma unroll
  for (int j = 0; j < 4; j++) {
    int gc = col0 + wc + j * 16 + fr;
    float bv = bfb[gc];
#pragma unroll
    for (int i = 0; i < 4; i++) {
      int gr0 = row0 + wr + i * 16 + quad * 4;
#pragma unroll
      for (int r = 0; r < 4; r++)
        out[(size_t)(gr0 + r) * DD + gc] = acc[i][j][r] + bv;
    }
  }
}

extern "C" void kernel_launch(void* const* d_in, const int* in_sizes, int n_in,
                              void* d_out, int out_size, void* d_ws, size_t ws_size,
                              hipStream_t stream) {
  const float* a   = (const float*)d_in[0];
  const float* b   = (const float*)d_in[1];
  const float* Wq  = (const float*)d_in[2];
  const float* bq  = (const float*)d_in[3];
  const float* Wk  = (const float*)d_in[4];
  const float* bk  = (const float*)d_in[5];
  const float* wg  = (const float*)d_in[6];
  const float* Wp  = (const float*)d_in[7];
  const float* bp  = (const float*)d_in[8];
  const float* Wf  = (const float*)d_in[9];
  const float* bfb = (const float*)d_in[10];

  unsigned short* ABab = (unsigned short*)d_ws;   // a|b bf16; later O1 (first MD)
  unsigned short* QK   = ABab + 2 * MD;           // Qraw | Kraw
  unsigned short* Wqkb = QK + 2 * MD;             // Wq | Wk bf16
  unsigned short* Wfb  = Wqkb + 2 * WELEM;
  unsigned short* Wps  = Wfb + WELEM;             // 8 per-batch scaled Wp
  float* SSQK = (float*)(Wps + 8 * WELEM);        // SSQ | SSK (2*MTOT)
  float* Adot = SSQK + 2 * MTOT;                  // MTOT (contiguous w/ SSQK for zeroing)
  float* rnQ  = Adot + MTOT;
  float* rnK  = rnQ + MTOT;
  float* wrow = rnK + MTOT;
  float* sinv = wrow + MTOT;
  float* G    = sinv + 64;

  cvt2_k<<<dim3(32768), dim3(256), 0, stream>>>(a, b, ABab);
  prep_k<<<dim3(864), dim3(256), 0, stream>>>(Wq, Wk, Wf, Wqkb, Wfb, SSQK);
  gemm_qk_k<<<dim3(256, 4, 2), dim3(256), 0, stream>>>(ABab, Wqkb, bq, bk, wg,
                                                       QK, SSQK, Adot);
  reduce2_k<<<dim3(8), dim3(1024), 0, stream>>>(SSQK, Adot, rnQ, rnK, wrow, sinv, G);
  pool_k<<<dim3(256), dim3(256), 0, stream>>>(wrow, sinv, QK, G);
  scalew_k<<<dim3(2048), dim3(256), 0, stream>>>(Wp, G, Wps);
  gemm3_k<<<dim3(256, 4), dim3(256), 0, stream>>>(QK + MD, Wps, bp, QK, rnK, rnQ, ABab);
  gemm4_k<<<dim3(256, 4), dim3(256), 0, stream>>>(ABab, Wfb, bfb, (float*)d_out);
}